// Round 10
// baseline (1792.029 us; speedup 1.0000x reference)
//
#include <hip/hip_runtime.h>
#include <stdint.h>

// RNNModel: h_{t+1} = hardtanh(x_t @ W_in^T + h_t @ W_h^T), out = h_T @ W_out^T
// B=1024 T=2048 D=13 H=128 O=2, fp32 in/out.
//
// Round 10: TWO independent 16-batch groups per block (NB=32, 8 waves).
//  r9 falsified the vmcnt-drain theory (lgkm barrier = null). Revised model:
//  per-step time = serialized phases (LDS-read jam -> MFMA -> epilogue VALU ->
//  barrier) because at 1 wave/SIMD every wave is in the same phase. Fix:
//  2 waves/SIMD from INDEPENDENT groups -> group A's MFMA overlaps group B's
//  LDS/VALU on the same SIMD. Per-batch LDS traffic unchanged (r7's mistake
//  doubled it). x-term MFMAs (no LDS dep) issue first, seeding accumulators
//  while h-fragment ds_reads are in flight.
//  Keeps: r6 cvt_pk epilogue, fragment-ordered LDS (1 b128 per (kt,hi|lo)),
//  depth-2 x prefetch in named scalars, lgkm-only in-loop barrier (r9: neutral,
//  theoretically cleaner).

#define RNN_B 1024
#define RNN_T 2048
#define RNN_D 13
#define RNN_H 128
#define RNN_O 2

#define NB 32                 // batches per block = 2 groups x 16
#define NWAVE 8
#define NTHR (NWAVE * 64)
#define ROWS 136              // shorts per batch row: 128 data + 8 pad (17 quads)

using f32x4 = __attribute__((ext_vector_type(4))) float;
using v8s   = __attribute__((ext_vector_type(8))) short;

__device__ __forceinline__ short f2bf(float f) {           // setup only
    union { float f; uint32_t u; } c; c.f = f;
    uint32_t u = c.u + 0x7fffu + ((c.u >> 16) & 1u);
    return (short)(u >> 16);
}
__device__ __forceinline__ float bf2fs(short s) {
    union { uint32_t u; float f; } c; c.u = ((uint32_t)(uint16_t)s) << 16;
    return c.f;
}
__device__ __forceinline__ float bitf(uint32_t u) {
    union { uint32_t u; float f; } c; c.u = u; return c.f;
}
__device__ __forceinline__ uint32_t cvtpk(float a, float b) {  // [bf16(b)|bf16(a)]
    uint32_t r;
    asm("v_cvt_pk_bf16_f32 %0, %1, %2" : "=v"(r) : "v"(a), "v"(b));
    return r;
}
__device__ __forceinline__ v8s pack4(uint32_t a, uint32_t b, uint32_t c, uint32_t d) {
    union { uint32_t u[4]; v8s s; } z;
    z.u[0] = a; z.u[1] = b; z.u[2] = c; z.u[3] = d; return z.s;
}
__device__ __forceinline__ float clamp1(float v) {
    return __builtin_amdgcn_fmed3f(v, -1.0f, 1.0f);
}

// lgkm-only workgroup barrier (global loads stay in flight across it)
__device__ __forceinline__ void barrier_lgkm() {
    __builtin_amdgcn_sched_barrier(0);
    asm volatile("s_waitcnt lgkmcnt(0)" ::: "memory");
    __builtin_amdgcn_s_barrier();
    asm volatile("" ::: "memory");
    __builtin_amdgcn_sched_barrier(0);
}

// one recurrence step; X0..X3 are named lvalue scalars (current x), refilled
// with x[TPF] (depth-2 prefetch). CUR/NXT are literal buffer indices.
#define STEP(CUR, NXT, X0, X1, X2, X3, TPF)                                      \
  do {                                                                           \
    /* 1) issue h-fragment reads (sit in lgkm queue) */                          \
    v8s bh[4], bl[4];                                                            \
    bh[0] = *(const v8s*)&Hhi[CUR][grp][n][g8];                                  \
    bh[1] = *(const v8s*)&Hhi[CUR][grp][n][32 + g8];                             \
    bh[2] = *(const v8s*)&Hhi[CUR][grp][n][64 + g8];                             \
    bh[3] = *(const v8s*)&Hhi[CUR][grp][n][96 + g8];                             \
    bl[0] = *(const v8s*)&Hlo[CUR][grp][n][g8];                                  \
    bl[1] = *(const v8s*)&Hlo[CUR][grp][n][32 + g8];                             \
    bl[2] = *(const v8s*)&Hlo[CUR][grp][n][64 + g8];                             \
    bl[3] = *(const v8s*)&Hlo[CUR][grp][n][96 + g8];                             \
    /* 2) x fragments (VALU only, overlaps LDS latency) */                       \
    float m0 = X0, m1 = X1, m2 = X2, m3 = X3;                                    \
    if (g == 3) { m1 = 0.0f; m2 = 0.0f; m3 = 0.0f; }                             \
    uint32_t xh01 = cvtpk(m0, m1), xh23 = cvtpk(m2, m3);                         \
    float q0 = m0 - bitf(xh01 << 16);                                            \
    float q1 = m1 - bitf(xh01 & 0xffff0000u);                                    \
    float q2 = m2 - bitf(xh23 << 16);                                            \
    float q3 = m3 - bitf(xh23 & 0xffff0000u);                                    \
    uint32_t xl01 = cvtpk(q0, q1), xl23 = cvtpk(q2, q3);                         \
    v8s xh = pack4(xh01, xh23, 0u, 0u);                                          \
    v8s xl = pack4(xl01, xl23, 0u, 0u);                                          \
    /* 3) x-term MFMAs seed the accumulators (no LDS dependence) */              \
    f32x4 Z = {0.f, 0.f, 0.f, 0.f};                                              \
    f32x4 A1 = __builtin_amdgcn_mfma_f32_16x16x32_bf16(whiA[4], xh, Z, 0,0,0);   \
    f32x4 B1 = __builtin_amdgcn_mfma_f32_16x16x32_bf16(whiB[4], xh, Z, 0,0,0);   \
    f32x4 A2 = __builtin_amdgcn_mfma_f32_16x16x32_bf16(whiA[4], xl, Z, 0,0,0);   \
    f32x4 B2 = __builtin_amdgcn_mfma_f32_16x16x32_bf16(whiB[4], xl, Z, 0,0,0);   \
    f32x4 A3 = __builtin_amdgcn_mfma_f32_16x16x32_bf16(wloA[4], xh, Z, 0,0,0);   \
    f32x4 B3 = __builtin_amdgcn_mfma_f32_16x16x32_bf16(wloB[4], xh, Z, 0,0,0);   \
    /* 4) prefetch x two steps ahead */                                          \
    if ((TPF) < RNN_T) {                                                         \
      const float* xp = xrow + (size_t)(TPF) * RNN_D;                            \
      X0 = xp[d0]; X1 = xp[d1]; X2 = xp[d2]; X3 = xp[d3];                        \
    }                                                                            \
    /* 5) h-term MFMAs as fragments arrive */                                    \
    _Pragma("unroll")                                                            \
    for (int kt = 0; kt < 4; ++kt) {                                             \
      A1 = __builtin_amdgcn_mfma_f32_16x16x32_bf16(whiA[kt], bh[kt], A1, 0,0,0); \
      B1 = __builtin_amdgcn_mfma_f32_16x16x32_bf16(whiB[kt], bh[kt], B1, 0,0,0); \
      A2 = __builtin_amdgcn_mfma_f32_16x16x32_bf16(whiA[kt], bl[kt], A2, 0,0,0); \
      B2 = __builtin_amdgcn_mfma_f32_16x16x32_bf16(whiB[kt], bl[kt], B2, 0,0,0); \
      A3 = __builtin_amdgcn_mfma_f32_16x16x32_bf16(wloA[kt], bh[kt], A3, 0,0,0); \
      B3 = __builtin_amdgcn_mfma_f32_16x16x32_bf16(wloB[kt], bh[kt], B3, 0,0,0); \
    }                                                                            \
    /* 6) epilogue per m-tile: sum, clip, split, packed b64 write */             \
    {                                                                            \
      float v0 = clamp1(A1[0] + A2[0] + A3[0]);                                  \
      float v1 = clamp1(A1[1] + A2[1] + A3[1]);                                  \
      float v2 = clamp1(A1[2] + A2[2] + A3[2]);                                  \
      float v3 = clamp1(A1[3] + A2[3] + A3[3]);                                  \
      uint32_t h01 = cvtpk(v0, v1), h23 = cvtpk(v2, v3);                         \
      float p0 = v0 - bitf(h01 << 16);                                           \
      float p1 = v1 - bitf(h01 & 0xffff0000u);                                   \
      float p2 = v2 - bitf(h23 << 16);                                           \
      float p3 = v3 - bitf(h23 & 0xffff0000u);                                   \
      uint32_t l01 = cvtpk(p0, p1), l23 = cvtpk(p2, p3);                         \
      int2 wv; wv.x = (int)h01; wv.y = (int)h23;                                 \
      *(int2*)&Hhi[NXT][grp][n][wbase + g8] = wv;                                \
      wv.x = (int)l01; wv.y = (int)l23;                                          \
      *(int2*)&Hlo[NXT][grp][n][wbase + g8] = wv;                                \
    }                                                                            \
    {                                                                            \
      float v0 = clamp1(B1[0] + B2[0] + B3[0]);                                  \
      float v1 = clamp1(B1[1] + B2[1] + B3[1]);                                  \
      float v2 = clamp1(B1[2] + B2[2] + B3[2]);                                  \
      float v3 = clamp1(B1[3] + B2[3] + B3[3]);                                  \
      uint32_t h01 = cvtpk(v0, v1), h23 = cvtpk(v2, v3);                         \
      float p0 = v0 - bitf(h01 << 16);                                           \
      float p1 = v1 - bitf(h01 & 0xffff0000u);                                   \
      float p2 = v2 - bitf(h23 << 16);                                           \
      float p3 = v3 - bitf(h23 & 0xffff0000u);                                   \
      uint32_t l01 = cvtpk(p0, p1), l23 = cvtpk(p2, p3);                         \
      int2 wv; wv.x = (int)h01; wv.y = (int)h23;                                 \
      *(int2*)&Hhi[NXT][grp][n][wbase + g8 + 4] = wv;                            \
      wv.x = (int)l01; wv.y = (int)l23;                                          \
      *(int2*)&Hlo[NXT][grp][n][wbase + g8 + 4] = wv;                            \
    }                                                                            \
    barrier_lgkm();                                                              \
  } while (0)

__global__ __launch_bounds__(NTHR, 1) void rnn_mfma10_kernel(
    const float* __restrict__ xs,     // [B, T, D]
    const float* __restrict__ W_in,   // [H, D]
    const float* __restrict__ W_h,    // [H, H]
    const float* __restrict__ W_out,  // [O, H]
    float* __restrict__ out)          // [B, O]
{
    __shared__ __align__(16) short Hhi[2][2][16][ROWS];   // [buf][group][n][pos]
    __shared__ __align__(16) short Hlo[2][2][16][ROWS];

    const int tid  = threadIdx.x;
    const int lane = tid & 63;
    const int wid  = tid >> 6;       // wave 0..7
    const int grp  = wid >> 2;       // group 0 or 1 (independent 16-batch GEMMs)
    const int wg   = wid & 3;        // wave-in-group = m-tile pair index
    const int n    = lane & 15;      // batch col / A-row within tile
    const int g    = lane >> 4;      // k-group 0..3
    const int g8   = g * 8;
    const int wbase = 32 * wg;       // write base: pos = 32*wg + 8g + 4*mi
    const int b0   = blockIdx.x * NB;

    // clamped x element indices for this lane (d = 4g+j, clamped into [0,12])
    const int d0 = (4 * g + 0 > 12) ? 12 : 4 * g + 0;
    const int d1 = (4 * g + 1 > 12) ? 12 : 4 * g + 1;
    const int d2 = (4 * g + 2 > 12) ? 12 : 4 * g + 2;
    const int d3 = (4 * g + 3 > 12) ? 12 : 4 * g + 3;

    // ---- A fragments: rows 16*(2*wg+mi)+n, bf16 hi/lo, 5 k-tiles ----
    // (identical for both groups — same weights)
    v8s whiA[5], wloA[5], whiB[5], wloB[5];
    #pragma unroll
    for (int mi = 0; mi < 2; ++mi) {
        const int row = 16 * (wg * 2 + mi) + n;
        #pragma unroll
        for (int kt = 0; kt < 5; ++kt) {
            v8s h8, l8;
            #pragma unroll
            for (int j = 0; j < 4; ++j) {
                float w1, w2;
                if (kt < 4) {
                    w1 = W_h[row * RNN_H + 32 * kt + 4 * g + j];
                    w2 = W_h[row * RNN_H + 32 * kt + 16 + 4 * g + j];
                } else {
                    const int kx = 4 * g + j;
                    w1 = (kx < RNN_D) ? W_in[row * RNN_D + kx] : 0.0f;
                    w2 = 0.0f;
                }
                const short h1 = f2bf(w1);
                const short h2 = f2bf(w2);
                h8[j] = h1; h8[4 + j] = h2;
                l8[j] = f2bf(w1 - bf2fs(h1));
                l8[4 + j] = f2bf(w2 - bf2fs(h2));
            }
            if (mi == 0) { whiA[kt] = h8; wloA[kt] = l8; }
            else         { whiB[kt] = h8; wloB[kt] = l8; }
        }
    }

    // ---- zero-init buffer 0 (h0 = 0): 2 groups x 16 x ROWS shorts ----
    for (int idx = tid; idx < 2 * 16 * ROWS; idx += NTHR) {
        (&Hhi[0][0][0][0])[idx] = 0;
        (&Hlo[0][0][0][0])[idx] = 0;
    }

    // ---- x prefetch depth 2, named scalars ----
    const float* xrow = xs + (size_t)(b0 + grp * 16 + n) * RNN_T * RNN_D;
    float xa0 = xrow[d0], xa1 = xrow[d1], xa2 = xrow[d2], xa3 = xrow[d3];
    float xb0 = xrow[RNN_D + d0], xb1 = xrow[RNN_D + d1];
    float xb2 = xrow[RNN_D + d2], xb3 = xrow[RNN_D + d3];
    __syncthreads();

    // ---- recurrence, x2 unrolled (buf 0 -> 1 -> 0 ...) ----
    for (int t = 0; t < RNN_T; t += 2) {
        STEP(0, 1, xa0, xa1, xa2, xa3, t + 2);
        STEP(1, 0, xb0, xb1, xb2, xb3, t + 3);
    }

    __syncthreads();  // full sync once before epilogue

    // ---- epilogue: out[b][o] = sum_i W_out[o][i] * h_T[i]  (final h in buf 0)
    // wave 0 handles group 0, wave 4 handles group 1.
    if (wg == 0 && lane < 16 * RNN_O) {
        const int nn = lane & 15;
        const int o  = lane >> 4;
        float acc = 0.0f;
        for (int i = 0; i < RNN_H; ++i) {
            const int pos = 32 * (i >> 5) + 8 * ((i >> 2) & 3)
                          + 4 * ((i >> 4) & 1) + (i & 3);
            const float hv = bf2fs(Hhi[0][grp][nn][pos]) + bf2fs(Hlo[0][grp][nn][pos]);
            acc = fmaf(W_out[o * RNN_H + i], hv, acc);
        }
        out[(size_t)(b0 + grp * 16 + nn) * RNN_O + o] = acc;
    }
}

extern "C" void kernel_launch(void* const* d_in, const int* in_sizes, int n_in,
                              void* d_out, int out_size, void* d_ws, size_t ws_size,
                              hipStream_t stream) {
    const float* xs    = (const float*)d_in[0];
    const float* W_in  = (const float*)d_in[1];
    const float* W_h   = (const float*)d_in[2];
    const float* W_out = (const float*)d_in[3];
    float* out = (float*)d_out;

    rnn_mfma10_kernel<<<RNN_B / NB, NTHR, 0, stream>>>(xs, W_in, W_h, W_out, out);
}

// Round 13
// 1211.490 us; speedup vs baseline: 1.4792x; 1.4792x over previous
//
#include <hip/hip_runtime.h>
#include <stdint.h>

// RNNModel: h_{t+1} = hardtanh(x_t @ W_in^T + h_t @ W_h^T), out = h_T @ W_out^T
// B=1024 T=2048 D=13 H=128 O=2, fp32 in/out.
//
// Round 12 (resubmit; prior run died on infra): self-fragment via ROTATION
// indexing — UNIFORM control flow.
//  r11 (self-frag + 4 divergent loop clones with barriers) failed (absmax 1.45,
//  decorrelated h). Suspect: s_barrier in wave-divergent control flow breaks
//  wave synchronization. Fix: single loop for all waves; fragment arrays are
//  stored ROTATED (wA[q] <-> kt=(wid+q)&3, rotation in setup load ADDRESSES,
//  array indices static). q=0 = self slice (register-forwarded selfB; D-frag
//  of wave wid IS the B-frag for kt=wid, same lane — bit-identical to the r6
//  LDS round-trip). q=1..3 = LDS reads at runtime-uniform offsets.
//  Also: A-tile epilogue interleaved between B-tile MFMA groups (independent
//  ops, pure placement) to hide epilogue VALU under MFMA issue.
//  Base otherwise = r6/r9 (4 waves x 2 m-tiles, NB=16, 64 blocks, cvt_pk
//  epilogue, fragment-ordered LDS pos = 32kt+8g+4h+j for k=32kt+16h+4g+j,
//  depth-2 x prefetch, lgkm-only barrier).

#define RNN_B 1024
#define RNN_T 2048
#define RNN_D 13
#define RNN_H 128
#define RNN_O 2

#define NB 16
#define NWAVE 4
#define NTHR (NWAVE * 64)
#define ROWS 136              // shorts per batch row: 128 data + 8 pad (17 quads)

using f32x4 = __attribute__((ext_vector_type(4))) float;
using v8s   = __attribute__((ext_vector_type(8))) short;

__device__ __forceinline__ short f2bf(float f) {           // setup only
    union { float f; uint32_t u; } c; c.f = f;
    uint32_t u = c.u + 0x7fffu + ((c.u >> 16) & 1u);
    return (short)(u >> 16);
}
__device__ __forceinline__ float bf2fs(short s) {
    union { uint32_t u; float f; } c; c.u = ((uint32_t)(uint16_t)s) << 16;
    return c.f;
}
__device__ __forceinline__ float bitf(uint32_t u) {
    union { uint32_t u; float f; } c; c.u = u; return c.f;
}
__device__ __forceinline__ uint32_t cvtpk(float a, float b) {  // [bf16(b)|bf16(a)]
    uint32_t r;
    asm("v_cvt_pk_bf16_f32 %0, %1, %2" : "=v"(r) : "v"(a), "v"(b));
    return r;
}
__device__ __forceinline__ v8s pack4(uint32_t a, uint32_t b, uint32_t c, uint32_t d) {
    union { uint32_t u[4]; v8s s; } z;
    z.u[0] = a; z.u[1] = b; z.u[2] = c; z.u[3] = d; return z.s;
}
__device__ __forceinline__ float clamp1(float v) {
    return __builtin_amdgcn_fmed3f(v, -1.0f, 1.0f);
}

// lgkm-only workgroup barrier (global loads stay in flight across it)
__device__ __forceinline__ void barrier_lgkm() {
    __builtin_amdgcn_sched_barrier(0);
    asm volatile("s_waitcnt lgkmcnt(0)" ::: "memory");
    __builtin_amdgcn_s_barrier();
    asm volatile("" ::: "memory");
    __builtin_amdgcn_sched_barrier(0);
}

#define MFMA(a, b, c) __builtin_amdgcn_mfma_f32_16x16x32_bf16((a), (b), (c), 0, 0, 0)

// One step, uniform for all waves. wA[q]/wB[q] are kt=(wid+q)&3 rotated.
// ktq1..3 = precomputed LDS short-offsets of the rotated kt slices.
#define STEP(CUR, NXT, X0, X1, X2, X3, TPF)                                      \
  do {                                                                           \
    /* 1) issue reads for q=1..3 (runtime-uniform offsets, static regs) */       \
    v8s bh1 = *(const v8s*)&Hhi[CUR][n][ktq1 + g8];                              \
    v8s bl1 = *(const v8s*)&Hlo[CUR][n][ktq1 + g8];                              \
    v8s bh2 = *(const v8s*)&Hhi[CUR][n][ktq2 + g8];                              \
    v8s bl2 = *(const v8s*)&Hlo[CUR][n][ktq2 + g8];                              \
    v8s bh3 = *(const v8s*)&Hhi[CUR][n][ktq3 + g8];                              \
    v8s bl3 = *(const v8s*)&Hlo[CUR][n][ktq3 + g8];                              \
    /* 2) x fragments (VALU; overlaps LDS latency) */                            \
    float m0 = X0, m1 = X1, m2 = X2, m3 = X3;                                    \
    if (g == 3) { m1 = 0.0f; m2 = 0.0f; m3 = 0.0f; }                             \
    uint32_t xh01 = cvtpk(m0, m1), xh23 = cvtpk(m2, m3);                         \
    float q0 = m0 - bitf(xh01 << 16);                                            \
    float q1 = m1 - bitf(xh01 & 0xffff0000u);                                    \
    float q2 = m2 - bitf(xh23 << 16);                                            \
    float q3 = m3 - bitf(xh23 & 0xffff0000u);                                    \
    uint32_t xl01 = cvtpk(q0, q1), xl23 = cvtpk(q2, q3);                         \
    v8s xh = pack4(xh01, xh23, 0u, 0u);                                          \
    v8s xl = pack4(xl01, xl23, 0u, 0u);                                          \
    /* 3) A-tile MFMAs: x + self first (reg-only), then q1..q3 */                \
    f32x4 Z = {0.f, 0.f, 0.f, 0.f};                                              \
    f32x4 A1 = MFMA(whiA[4], xh, Z);                                             \
    f32x4 A2 = MFMA(whiA[4], xl, Z);                                             \
    f32x4 A3 = MFMA(wloA[4], xh, Z);                                             \
    A1 = MFMA(whiA[0], selfBh, A1);                                              \
    A2 = MFMA(whiA[0], selfBl, A2);                                              \
    A3 = MFMA(wloA[0], selfBh, A3);                                              \
    /* 4) x prefetch two steps ahead (stays in vmcnt across barriers) */         \
    if ((TPF) < RNN_T) {                                                         \
      const float* xp = xrow + (size_t)(TPF) * RNN_D;                            \
      X0 = xp[d0]; X1 = xp[d1]; X2 = xp[d2]; X3 = xp[d3];                        \
    }                                                                            \
    A1 = MFMA(whiA[1], bh1, A1);                                                 \
    A2 = MFMA(whiA[1], bl1, A2);                                                 \
    A3 = MFMA(wloA[1], bh1, A3);                                                 \
    A1 = MFMA(whiA[2], bh2, A1);                                                 \
    A2 = MFMA(whiA[2], bl2, A2);                                                 \
    A3 = MFMA(wloA[2], bh2, A3);                                                 \
    A1 = MFMA(whiA[3], bh3, A1);                                                 \
    A2 = MFMA(whiA[3], bl3, A2);                                                 \
    A3 = MFMA(wloA[3], bh3, A3);                                                 \
    /* 5) B-tile x+self MFMAs, interleaved with A epilogue chunks */             \
    f32x4 B1 = MFMA(whiB[4], xh, Z);                                             \
    f32x4 B2 = MFMA(whiB[4], xl, Z);                                             \
    f32x4 B3 = MFMA(wloB[4], xh, Z);                                             \
    B1 = MFMA(whiB[0], selfBh, B1);                                              \
    B2 = MFMA(whiB[0], selfBl, B2);                                              \
    B3 = MFMA(wloB[0], selfBh, B3);                                              \
    float v0 = clamp1(A1[0] + A2[0] + A3[0]);                                    \
    float v1 = clamp1(A1[1] + A2[1] + A3[1]);                                    \
    float v2 = clamp1(A1[2] + A2[2] + A3[2]);                                    \
    float v3 = clamp1(A1[3] + A2[3] + A3[3]);                                    \
    B1 = MFMA(whiB[1], bh1, B1);                                                 \
    B2 = MFMA(whiB[1], bl1, B2);                                                 \
    B3 = MFMA(wloB[1], bh1, B3);                                                 \
    uint32_t h01A = cvtpk(v0, v1), h23A = cvtpk(v2, v3);                         \
    float p0 = v0 - bitf(h01A << 16);                                            \
    float p1 = v1 - bitf(h01A & 0xffff0000u);                                    \
    float p2 = v2 - bitf(h23A << 16);                                            \
    float p3 = v3 - bitf(h23A & 0xffff0000u);                                    \
    B1 = MFMA(whiB[2], bh2, B1);                                                 \
    B2 = MFMA(whiB[2], bl2, B2);                                                 \
    B3 = MFMA(wloB[2], bh2, B3);                                                 \
    uint32_t l01A = cvtpk(p0, p1), l23A = cvtpk(p2, p3);                         \
    {                                                                            \
      int2 wv; wv.x = (int)h01A; wv.y = (int)h23A;                               \
      *(int2*)&Hhi[NXT][n][wbase + g8] = wv;                                     \
      wv.x = (int)l01A; wv.y = (int)l23A;                                        \
      *(int2*)&Hlo[NXT][n][wbase + g8] = wv;                                     \
    }                                                                            \
    B1 = MFMA(whiB[3], bh3, B1);                                                 \
    B2 = MFMA(whiB[3], bl3, B2);                                                 \
    B3 = MFMA(wloB[3], bh3, B3);                                                 \
    /* 6) B epilogue + self-fragment assembly */                                 \
    {                                                                            \
      float w0 = clamp1(B1[0] + B2[0] + B3[0]);                                  \
      float w1 = clamp1(B1[1] + B2[1] + B3[1]);                                  \
      float w2 = clamp1(B1[2] + B2[2] + B3[2]);                                  \
      float w3 = clamp1(B1[3] + B2[3] + B3[3]);                                  \
      uint32_t h01B = cvtpk(w0, w1), h23B = cvtpk(w2, w3);                       \
      float r0 = w0 - bitf(h01B << 16);                                          \
      float r1 = w1 - bitf(h01B & 0xffff0000u);                                  \
      float r2 = w2 - bitf(h23B << 16);                                          \
      float r3 = w3 - bitf(h23B & 0xffff0000u);                                  \
      uint32_t l01B = cvtpk(r0, r1), l23B = cvtpk(r2, r3);                       \
      selfBh = pack4(h01A, h23A, h01B, h23B);                                    \
      selfBl = pack4(l01A, l23A, l01B, l23B);                                    \
      int2 wv; wv.x = (int)h01B; wv.y = (int)h23B;                               \
      *(int2*)&Hhi[NXT][n][wbase + g8 + 4] = wv;                                 \
      wv.x = (int)l01B; wv.y = (int)l23B;                                        \
      *(int2*)&Hlo[NXT][n][wbase + g8 + 4] = wv;                                 \
    }                                                                            \
    barrier_lgkm();                                                              \
  } while (0)

__global__ __launch_bounds__(NTHR, 1) void rnn_mfma12_kernel(
    const float* __restrict__ xs,     // [B, T, D]
    const float* __restrict__ W_in,   // [H, D]
    const float* __restrict__ W_h,    // [H, H]
    const float* __restrict__ W_out,  // [O, H]
    float* __restrict__ out)          // [B, O]
{
    __shared__ __align__(16) short Hhi[2][NB][ROWS];
    __shared__ __align__(16) short Hlo[2][NB][ROWS];

    const int tid  = threadIdx.x;
    const int lane = tid & 63;
    const int wid  = tid >> 6;       // wave 0..3; self kt = wid
    const int n    = lane & 15;      // batch col / A-row within tile
    const int g    = lane >> 4;      // k-group 0..3
    const int g8   = g * 8;
    const int wbase = 32 * wid;      // write base: pos = 32*wid + 8g + 4*mi
    const int b0   = blockIdx.x * NB;

    // rotated kt short-offsets for q=1..3 (runtime-uniform, used in addresses)
    const int ktq1 = ((wid + 1) & 3) * 32;
    const int ktq2 = ((wid + 2) & 3) * 32;
    const int ktq3 = ((wid + 3) & 3) * 32;

    // clamped x element indices for this lane (d = 4g+j, clamped into [0,12])
    const int d0 = (4 * g + 0 > 12) ? 12 : 4 * g + 0;
    const int d1 = (4 * g + 1 > 12) ? 12 : 4 * g + 1;
    const int d2 = (4 * g + 2 > 12) ? 12 : 4 * g + 2;
    const int d3 = (4 * g + 3 > 12) ? 12 : 4 * g + 3;

    // ---- A fragments, ROTATED: wA[q] <-> kt=(wid+q)&3; index 4 = x tile ----
    v8s whiA[5], wloA[5], whiB[5], wloB[5];
    #pragma unroll
    for (int mi = 0; mi < 2; ++mi) {
        const int row = 16 * (wid * 2 + mi) + n;
        #pragma unroll
        for (int q = 0; q < 4; ++q) {
            const int kt = (wid + q) & 3;          // runtime; addresses only
            v8s h8, l8;
            #pragma unroll
            for (int j = 0; j < 4; ++j) {
                const float w1 = W_h[row * RNN_H + 32 * kt + 4 * g + j];
                const float w2 = W_h[row * RNN_H + 32 * kt + 16 + 4 * g + j];
                const short h1 = f2bf(w1);
                const short h2 = f2bf(w2);
                h8[j] = h1; h8[4 + j] = h2;
                l8[j] = f2bf(w1 - bf2fs(h1));
                l8[4 + j] = f2bf(w2 - bf2fs(h2));
            }
            if (mi == 0) { whiA[q] = h8; wloA[q] = l8; }
            else         { whiB[q] = h8; wloB[q] = l8; }
        }
        {   // x tile (index 4)
            v8s h8, l8;
            #pragma unroll
            for (int j = 0; j < 4; ++j) {
                const int kx = 4 * g + j;
                const float w1 = (kx < RNN_D) ? W_in[row * RNN_D + kx] : 0.0f;
                const short h1 = f2bf(w1);
                h8[j] = h1; h8[4 + j] = 0;
                l8[j] = f2bf(w1 - bf2fs(h1));
                l8[4 + j] = 0;
            }
            if (mi == 0) { whiA[4] = h8; wloA[4] = l8; }
            else         { whiB[4] = h8; wloB[4] = l8; }
        }
    }

    // ---- zero-init buffer 0 (h0 = 0) ----
    for (int idx = tid; idx < NB * ROWS; idx += NTHR) {
        (&Hhi[0][0][0])[idx] = 0;
        (&Hlo[0][0][0])[idx] = 0;
    }

    // ---- self B-fragment (kt = wid) starts at h0 = 0 ----
    v8s selfBh = {0, 0, 0, 0, 0, 0, 0, 0};
    v8s selfBl = {0, 0, 0, 0, 0, 0, 0, 0};

    // ---- x prefetch depth 2, named scalars ----
    const float* xrow = xs + (size_t)(b0 + n) * RNN_T * RNN_D;
    float xa0 = xrow[d0], xa1 = xrow[d1], xa2 = xrow[d2], xa3 = xrow[d3];
    float xb0 = xrow[RNN_D + d0], xb1 = xrow[RNN_D + d1];
    float xb2 = xrow[RNN_D + d2], xb3 = xrow[RNN_D + d3];
    __syncthreads();

    // ---- recurrence: SINGLE uniform loop for all waves ----
    for (int t = 0; t < RNN_T; t += 2) {
        STEP(0, 1, xa0, xa1, xa2, xa3, t + 2);
        STEP(1, 0, xb0, xb1, xb2, xb3, t + 3);
    }

    __syncthreads();  // full sync once before epilogue

    // ---- epilogue: out[b][o] = sum_i W_out[o][i] * h_T[i]  (final h in buf 0) ----
    if (wid == 0 && lane < NB * RNN_O) {
        const int nn = lane & 15;
        const int o  = lane >> 4;
        float acc = 0.0f;
        for (int i = 0; i < RNN_H; ++i) {
            const int pos = 32 * (i >> 5) + 8 * ((i >> 2) & 3)
                          + 4 * ((i >> 4) & 1) + (i & 3);
            const float hv = bf2fs(Hhi[0][nn][pos]) + bf2fs(Hlo[0][nn][pos]);
            acc = fmaf(W_out[o * RNN_H + i], hv, acc);
        }
        out[(size_t)(b0 + nn) * RNN_O + o] = acc;
    }
}

extern "C" void kernel_launch(void* const* d_in, const int* in_sizes, int n_in,
                              void* d_out, int out_size, void* d_ws, size_t ws_size,
                              hipStream_t stream) {
    const float* xs    = (const float*)d_in[0];
    const float* W_in  = (const float*)d_in[1];
    const float* W_h   = (const float*)d_in[2];
    const float* W_out = (const float*)d_in[3];
    float* out = (float*)d_out;

    rnn_mfma12_kernel<<<RNN_B / NB, NTHR, 0, stream>>>(xs, W_in, W_h, W_out, out);
}